// Round 12
// baseline (2103.934 us; speedup 1.0000x reference)
//
#include <hip/hip_runtime.h>
#include <math.h>

// Problem constants
#define TT 8
#define BB 8
#define CC 64
#define HH 96
#define WW 96
#define LL 2
#define HW   (HH * WW)            // 9216
#define CHW  (CC * HW)            // 589824
#define BCHW (BB * CHW)           // 4718592
#define TBCHW (TT * BCHW)         // 37748736
#define WSZ  (CC * CC * 9)        // 36864 (per-layer weight tensor, fp32 elems)

typedef _Float16 f16;
typedef __attribute__((ext_vector_type(8))) _Float16 f16x8;
typedef __attribute__((ext_vector_type(4))) _Float16 f16x4;
typedef __attribute__((ext_vector_type(4))) float f32x4;

__device__ __forceinline__ float sigmoidf_(float x) {
    return 1.0f / (1.0f + __expf(-x));
}
// fast tanh: 1 - 2/(e^{2x}+1); saturates correctly at +-inf
__device__ __forceinline__ float tanhf_(float x) {
    float e = __expf(2.f * x);
    return 1.f - 2.f / (e + 1.f);
}

// ============================================================================
// R9 structure + gate-PAIR blocks (X staged once per pair instead of per gate):
//  - pairs (i,f) and (c,o) have IDENTICAL section sets (x,h,c / x,h), so one
//    block stages each X (sec,half) tile once and runs 2 MFMA phases on it.
//  - X dbuf (2x37.6KB) + W dbuf (2x36.9KB) = 149KB LDS, 1 block/CU.
//  - X staging volume halves (144->72 MB/step); W unchanged (L2-cacheable,
//    0.74MB unique); block rounds 3 -> 1.5.
// Padded activation slot: [B][98y][98x][64ci] f16, 128B/pixel, borders zero,
//   within each 64B half, chunk position p holds source chunk (p ^ x_pad)&3.
// Weight image per (layer,tensor): [half][tap][co][4 chunks][8 f16] = 73728 B,
//   chunk position p holds source chunk (p ^ co)&3.
// G: [4 gates][b][9216 pix][64 ci] f16 channel-last (no bias).
// ============================================================================

#define SLOT_B   9834496ull          // 8b * 98*98 * 128 bytes per padded slot
#define PLANE_B  1229312ull          // 98*98*128 (per-b plane bytes)
#define SLOT_F   (SLOT_B / 2)        // f16 elems per slot
#define GPLANE_F 4718592ull          // 8b*9216*64 f16 per gate plane
#define WT_F     36864               // f16 elems per (layer,tensor) weight image
#define XHALF_F  18816               // f16 per X buffer (6*98*32)
#define WHALF_F  18432               // f16 per W buffer (9*64*32)

struct WPtrs { const float* p[10]; };

__device__ __forceinline__ void gl_lds16(const void* g, void* lds_base) {
    __builtin_amdgcn_global_load_lds(
        (const __attribute__((address_space(1))) unsigned int*)g,
        (__attribute__((address_space(3))) unsigned int*)lds_base, 16, 0, 0);
}

// ---------- prep: weights fp32 -> f16 image ----------
__global__ __launch_bounds__(256) void wprep(WPtrs wsrcs, f16* Wf) {
    const int tap = blockIdx.x, ti = blockIdx.y, l = blockIdx.z;
    const float* src = wsrcs.p[ti] + l * WSZ;
    f16* dst = Wf + (size_t)(l * 10 + ti) * WT_F;
    for (int r = 0; r < 16; ++r) {
        int lin = r * 256 + threadIdx.x;      // 0..4095
        int co = lin >> 6, ci = lin & 63;
        float v = src[(co * 64 + ci) * 9 + tap];
        int half = ci >> 5, e = ci & 31, s = e >> 3;
        int p = (s ^ co) & 3;
        dst[((half * 9 + tap) * 64 + co) * 32 + p * 8 + (e & 7)] = (f16)v;
    }
}

// ---------- prep: zero borders of the 10 padded slots ----------
__global__ __launch_bounds__(256) void bzero(char* slots) {
    unsigned u = blockIdx.x * 256 + threadIdx.x;
    if (u >= 248320u) return;                  // 10 bufs * 8b * 388 px * 8 chunks
    unsigned plane = u / 3104u;                // [buf][b] composite (80 planes)
    unsigned r = u % 3104u;
    unsigned i = r >> 3, c = r & 7;
    int y, x;
    if (i < 98)       { y = 0;           x = i; }
    else if (i < 196) { y = 97;          x = i - 98; }
    else if (i < 292) { y = i - 196 + 1; x = 0; }
    else              { y = i - 292 + 1; x = 97; }
    uint4 z = make_uint4(0, 0, 0, 0);
    *(uint4*)(slots + (size_t)plane * PLANE_B + (size_t)(y * 98 + x) * 128 + c * 16) = z;
}

// ---------- prep: x fp32 -> padded f16 slots ----------
__global__ __launch_bounds__(256) void xprep(const float* __restrict__ x, f16* slots) {
    const int t = blockIdx.y;
    const int b = blockIdx.x / 96, y = blockIdx.x % 96;
    f16* slot = slots + (size_t)t * SLOT_F;
    for (int r = 0; r < 3; ++r) {
        int u = r * 256 + threadIdx.x;         // 0..767
        int px = u >> 3, c = u & 7;
        int half = c >> 2, p = c & 3;
        int sc = (p ^ (px + 1)) & 3;           // source chunk for position p
        int ci0 = half * 32 + sc * 8;
        const float* sp = x + ((((size_t)t * BB + b) * CC + ci0) * HH + y) * WW + px;
        union { f16 h[8]; uint4 q; } pk;
#pragma unroll
        for (int j = 0; j < 8; ++j) pk.h[j] = (f16)sp[(size_t)j * HW];
        f16* dp = slot + ((size_t)b * 9604 + (y + 1) * 98 + (px + 1)) * 64 + half * 32 + p * 8;
        *(uint4*)dp = pk.q;
    }
}

// ---------- staging helpers (gl_lds DMA) ----------
__device__ __forceinline__ void stage_x(const char* __restrict__ xb_h, int y0,
                                        int w, int lane, f16* Xs) {
    const char* xc = xb_h + (size_t)y0 * 12544;     // y0*98*128
    const int cb = w * 588;
#pragma unroll
    for (int i = 0; i < 9; ++i) {
        const int c = cb + i * 64 + lane;
        gl_lds16(xc + (size_t)(c >> 2) * 128 + (c & 3) * 16,
                 (char*)Xs + (size_t)(cb + i * 64) * 16);
    }
    if (lane < 12) {
        const int c = cb + 576 + lane;
        gl_lds16(xc + (size_t)(c >> 2) * 128 + (c & 3) * 16,
                 (char*)Xs + (size_t)(cb + 576) * 16);
    }
}
__device__ __forceinline__ void stage_w(const char* __restrict__ wsec_h,
                                        int w, int lane, f16* Wl) {
    const int cw = w * 576;
#pragma unroll
    for (int i = 0; i < 9; ++i) {
        gl_lds16(wsec_h + (size_t)(cw + i * 64 + lane) * 16,
                 (char*)Wl + (size_t)(cw + i * 64) * 16);
    }
}

// ---------- MFMA sweep over 9 taps for one (sec,half) phase ----------
__device__ __forceinline__ void mfma_phase(const f16* Xs, const f16* Wl,
                                           int w, int aBase, int d0, int d1, int d2,
                                           f32x4 acc[4][6]) {
#pragma unroll
    for (int tap = 0; tap < 9; ++tap) {
        const int dy = tap / 3, dx = tap % 3;
        const f16* Ar = &Wl[tap * 2048 + aBase];
        f16x8 a0 = *(const f16x8*)(Ar);
        f16x8 a1 = *(const f16x8*)(Ar + 512);
        f16x8 a2 = *(const f16x8*)(Ar + 1024);
        f16x8 a3 = *(const f16x8*)(Ar + 1536);
        const int doff = (dx == 0) ? d0 : (dx == 1) ? d1 : d2;
        const f16* Br = &Xs[(w + dy) * 3136 + doff];
#pragma unroll
        for (int nt = 0; nt < 6; ++nt) {
            f16x8 bf = *(const f16x8*)(Br + nt * 512);
            acc[0][nt] = __builtin_amdgcn_mfma_f32_16x16x32_f16(a0, bf, acc[0][nt], 0, 0, 0);
            acc[1][nt] = __builtin_amdgcn_mfma_f32_16x16x32_f16(a1, bf, acc[1][nt], 0, 0, 0);
            acc[2][nt] = __builtin_amdgcn_mfma_f32_16x16x32_f16(a2, bf, acc[2][nt], 0, 0, 0);
            acc[3][nt] = __builtin_amdgcn_mfma_f32_16x16x32_f16(a3, bf, acc[3][nt], 0, 0, 0);
        }
    }
}

struct GArgsN {
    const f16* in[3];       // padded slot bases (x, h, c); dups for unused
    const f16* w[4][3];     // weight image bases [gate][section]
    f16* G;                 // [4][b][9216][64] channel-last
    int nsecA, nsecB;       // section counts: pair (0,1) / pair (2,3)
};

// uniform select helpers (avoid runtime-indexed pointer arrays, rule #20)
__device__ __forceinline__ const char* wsel(const GArgsN& A, int gate, int sec) {
    const char* r;
    if (gate == 0)      r = (const char*)((sec == 0) ? A.w[0][0] : (sec == 1) ? A.w[0][1] : A.w[0][2]);
    else if (gate == 1) r = (const char*)((sec == 0) ? A.w[1][0] : (sec == 1) ? A.w[1][1] : A.w[1][2]);
    else if (gate == 2) r = (const char*)((sec == 0) ? A.w[2][0] : A.w[2][1]);
    else                r = (const char*)((sec == 0) ? A.w[3][0] : A.w[3][1]);
    return r;
}

// Grid 384 flat: b = bid&7 (XCD locality), gp = (bid>>3)&1, ytile = bid>>4.
// Block 256 (4 waves), 1 block/CU (149 KB LDS). Per (sec,half) super-phase:
// one X stage feeds TWO gate phases (accA for gate gp*2, accB for gp*2+1).
__global__ __launch_bounds__(256, 1) void gates_pair(GArgsN A) {
    __shared__ __align__(16) f16 Xs[2 * XHALF_F];
    __shared__ __align__(16) f16 Wl[2 * WHALF_F];
    const int bid = blockIdx.x;
    const int b = bid & 7, u = bid >> 3;
    const int gp = u & 1, y0 = (u >> 1) * 4;
    const int tid = threadIdx.x, w = tid >> 6, lane = tid & 63;
    const int pxl = lane & 15, kg = lane >> 4;
    const int gA = gp * 2, gB = gp * 2 + 1;
    const int nsec = gp ? A.nsecB : A.nsecA;
    const int K = 2 * nsec;                      // (sec,half) super-phases

    const int aBase = pxl * 32 + (((kg ^ pxl) & 3) << 3);
    const int d0 = (pxl + 0) * 32 + (((kg ^ (pxl + 0)) & 3) << 3);
    const int d1 = (pxl + 1) * 32 + (((kg ^ (pxl + 1)) & 3) << 3);
    const int d2 = (pxl + 2) * 32 + (((kg ^ (pxl + 2)) & 3) << 3);

    f32x4 accA[4][6], accB[4][6];
#pragma unroll
    for (int mt = 0; mt < 4; ++mt)
#pragma unroll
        for (int nt = 0; nt < 6; ++nt) {
            accA[mt][nt] = (f32x4){0.f, 0.f, 0.f, 0.f};
            accB[mt][nt] = (f32x4){0.f, 0.f, 0.f, 0.f};
        }

    const char* xb0 = (const char*)(A.in[0] + (size_t)b * 614656);   // 9604*64
    const char* xb1 = (const char*)(A.in[1] + (size_t)b * 614656);
    const char* xb2 = (const char*)(A.in[2] + (size_t)b * 614656);

    // prologue: X(k=0) -> Xbuf0, W(gA, k=0) -> Wbuf0
    stage_x(xb0, y0, w, lane, Xs);
    stage_w(wsel(A, gA, 0), w, lane, Wl);
    __syncthreads();

    for (int k = 0; k < K; ++k) {
        const int cur = k & 1;
        const int s = k >> 1, h = k & 1;
        if (k + 1 < K) {                         // prefetch next X tile
            const int s1 = (k + 1) >> 1, h1 = (k + 1) & 1;
            const char* xbn = (s1 == 0) ? xb0 : (s1 == 1) ? xb1 : xb2;
            stage_x(xbn + h1 * 64, y0, w, lane, Xs + ((k + 1) & 1) * XHALF_F);
        }
        stage_w(wsel(A, gB, s) + h * 36864, w, lane, Wl + WHALF_F);   // W(gB,k)
        mfma_phase(Xs + cur * XHALF_F, Wl, w, aBase, d0, d1, d2, accA);
        __syncthreads();                         // drain X(k+1), W(gB,k)
        if (k + 1 < K) {
            const int s1 = (k + 1) >> 1, h1 = (k + 1) & 1;
            stage_w(wsel(A, gA, s1) + h1 * 36864, w, lane, Wl);       // W(gA,k+1)
        }
        mfma_phase(Xs + cur * XHALF_F, Wl + WHALF_F, w, aBase, d0, d1, d2, accB);
        __syncthreads();                         // drain W(gA,k+1); Xbuf[cur] free
    }

    // epilogues: channel-last G writes for both gates
    const size_t rowoff = ((size_t)b * 9216 + (y0 + w) * 96) * 64;
    {
        f16* Gg = A.G + (size_t)gA * GPLANE_F + rowoff;
#pragma unroll
        for (int mt = 0; mt < 4; ++mt)
#pragma unroll
            for (int nt = 0; nt < 6; ++nt) {
                union { f16 h[4]; uint2 q; } pk;
#pragma unroll
                for (int r = 0; r < 4; ++r) pk.h[r] = (f16)accA[mt][nt][r];
                *(uint2*)(Gg + (size_t)(nt * 16 + pxl) * 64 + mt * 16 + kg * 4) = pk.q;
            }
    }
    {
        f16* Gg = A.G + (size_t)gB * GPLANE_F + rowoff;
#pragma unroll
        for (int mt = 0; mt < 4; ++mt)
#pragma unroll
            for (int nt = 0; nt < 6; ++nt) {
                union { f16 h[4]; uint2 q; } pk;
#pragma unroll
                for (int r = 0; r < 4; ++r) pk.h[r] = (f16)accB[mt][nt][r];
                *(uint2*)(Gg + (size_t)(nt * 16 + pxl) * 64 + mt * 16 + kg * 4) = pk.q;
            }
    }
}

// ---------- pointwise: gates -> c_new (f16 padded slot, + optional cs fp32) ----------
// Grid 2304 flat: b = bid&7 (XCD locality), u = bid>>3.
__global__ __launch_bounds__(256) void pointwise_n(const f16* __restrict__ G,
                                                   const f16* __restrict__ cprev,  // padded slot or null
                                                   const float* __restrict__ bi,
                                                   const float* __restrict__ bf,
                                                   const float* __restrict__ bc,
                                                   f16* __restrict__ cnew,          // padded slot
                                                   float* __restrict__ cs_out) {    // channel-first or null
    const int bid = blockIdx.x;
    const int b = bid & 7;
    const int u = (bid >> 3) * 256 + threadIdx.x;   // 0..73727
    const int pix = u >> 3, o = u & 7;
    const int ci0 = o * 8;
    const size_t goff = ((size_t)b * 9216 + pix) * 64 + ci0;
    const f16x8 gi = *(const f16x8*)(G + goff);
    const f16x8 gf = *(const f16x8*)(G + GPLANE_F + goff);
    const f16x8 gc = *(const f16x8*)(G + 2 * GPLANE_F + goff);
    const int py = pix / 96 + 1, pxp = pix % 96 + 1;
    const size_t pad_off = ((size_t)b * 9604 + py * 98 + pxp) * 64;
    const int half = o >> 2, p = ((o & 3) ^ pxp) & 3;
    const size_t sw_off = pad_off + half * 32 + p * 8;
    f16x8 cp = (f16x8)(_Float16)0.f;
    if (cprev) cp = *(const f16x8*)(cprev + sw_off);
    union { f16 h[8]; uint4 q; } outp;
    float cv[8];
#pragma unroll
    for (int j = 0; j < 8; ++j) {
        float vbi = bi[ci0 + j], vbf = bf[ci0 + j], vbc = bc[ci0 + j];
        float c = tanhf_((float)gc[j] + vbc) * sigmoidf_((float)gi[j] + vbi)
                + (float)cp[j] * sigmoidf_((float)gf[j] + vbf);
        cv[j] = c;
        outp.h[j] = (f16)c;
    }
    *(uint4*)(cnew + sw_off) = outp.q;
    if (cs_out) {
        float* op = cs_out + (size_t)b * CHW + (size_t)ci0 * HW + pix;
#pragma unroll
        for (int j = 0; j < 8; ++j) op[(size_t)j * HW] = cv[j];
    }
}

// ---------- out: h = sigmoid(conv(c_new,Whc)+Go+bo+bc) * tanh(c_new) ----------
// Grid 192 flat: b = bid&7, ytile = bid>>3. X+W dbuf pipeline, NP=2.
__global__ __launch_bounds__(256, 1) void out_n(const f16* __restrict__ cnew,   // padded slot
                                                const f16* __restrict__ whc,    // weight image
                                                const f16* __restrict__ Go,     // G plane 3
                                                const float* __restrict__ bo,
                                                const float* __restrict__ bc,
                                                f16* __restrict__ hslot,        // padded slot
                                                float* __restrict__ hs_out) {   // or null
    __shared__ __align__(16) f16 Xs[2 * XHALF_F];
    __shared__ __align__(16) f16 Wl[2 * WHALF_F];
    const int bid = blockIdx.x;
    const int b = bid & 7, y0 = (bid >> 3) * 4;
    const int tid = threadIdx.x, w = tid >> 6, lane = tid & 63;
    const int pxl = lane & 15, kg = lane >> 4;

    const int aBase = pxl * 32 + (((kg ^ pxl) & 3) << 3);
    const int d0 = (pxl + 0) * 32 + (((kg ^ (pxl + 0)) & 3) << 3);
    const int d1 = (pxl + 1) * 32 + (((kg ^ (pxl + 1)) & 3) << 3);
    const int d2 = (pxl + 2) * 32 + (((kg ^ (pxl + 2)) & 3) << 3);

    f32x4 acc[4][6];
#pragma unroll
    for (int mt = 0; mt < 4; ++mt)
#pragma unroll
        for (int nt = 0; nt < 6; ++nt) acc[mt][nt] = (f32x4){0.f, 0.f, 0.f, 0.f};

    const char* xb = (const char*)(cnew + (size_t)b * 614656);
    stage_x(xb, y0, w, lane, Xs);
    stage_w((const char*)whc, w, lane, Wl);
    __syncthreads();
    for (int p = 0; p < 2; ++p) {
        const int cur = p & 1;
        if (p == 0) {
            stage_x(xb + 64, y0, w, lane, Xs + XHALF_F);
            stage_w((const char*)whc + 36864, w, lane, Wl + WHALF_F);
        }
        mfma_phase(Xs + cur * XHALF_F, Wl + cur * WHALF_F,
                   w, aBase, d0, d1, d2, acc);
        __syncthreads();
    }

    const int y = y0 + w;
#pragma unroll
    for (int mt = 0; mt < 4; ++mt) {
        const int cob = mt * 16 + kg * 4;
        float vb[4];
#pragma unroll
        for (int r = 0; r < 4; ++r) vb[r] = bo[cob + r] + bc[cob + r];
        const int half = mt >> 1;                          // (cob>>5)
        const int sq = (mt * 2 + (kg >> 1)) & 3;           // ((cob&31)>>3)
        const int lo4 = (kg & 1) * 4;                      // (cob&7)
#pragma unroll
        for (int nt = 0; nt < 6; ++nt) {
            const int px = nt * 16 + pxl;
            const int pix = y * 96 + px;
            const size_t pad_off = ((size_t)b * 9604 + (y + 1) * 98 + (px + 1)) * 64;
            const int p = (sq ^ (px + 1)) & 3;
            const size_t qoff = pad_off + half * 32 + p * 8 + lo4;
            f16x4 cq = *(const f16x4*)(cnew + qoff);
            f16x4 gq = *(const f16x4*)(Go + ((size_t)b * 9216 + pix) * 64 + cob);
            union { f16 h[4]; uint2 q; } hq;
            float hv[4];
#pragma unroll
            for (int r = 0; r < 4; ++r) {
                float opre = acc[mt][nt][r] + (float)gq[r] + vb[r];
                hv[r] = sigmoidf_(opre) * tanhf_((float)cq[r]);
                hq.h[r] = (f16)hv[r];
            }
            *(uint2*)(hslot + qoff) = hq.q;
            if (hs_out) {
                float* op = hs_out + (size_t)b * CHW + (size_t)cob * HW + pix;
#pragma unroll
                for (int r = 0; r < 4; ++r) op[(size_t)r * HW] = hv[r];
            }
        }
    }
}

// ============================================================================
// FALLBACK PATH (round-3 kernels, ws budget 75.5 MB)
// ============================================================================

#define XROW 3136
#define XSZ  (6 * XROW)
#define WROW 2048
#define WSZL (9 * WROW)

__device__ __forceinline__ void conv_section(
    const float* __restrict__ inb, const float* __restrict__ wp,
    int y0, int tid, f16* Xs, f16* Wl,
    int w, int aBase, int d0, int d1, int d2, f32x4 acc[4][6])
{
    for (int ci0 = 0; ci0 < 64; ci0 += 32) {
        __syncthreads();
        for (int i = tid; i < 9408; i += 256) {
            int x = i % 98; int r = i / 98; int yy = r % 6; int c2 = r / 6;
            int gy = y0 - 1 + yy, gx = x - 1;
            float v0 = 0.f, v1 = 0.f;
            if ((unsigned)gy < 96u && (unsigned)gx < 96u) {
                const float* p = inb + (size_t)(ci0 + 2 * c2) * HW + gy * WW + gx;
                v0 = p[0]; v1 = p[HW];
            }
            union { f16 h[2]; unsigned u; } pk;
            pk.h[0] = (f16)v0; pk.h[1] = (f16)v1;
            int e = 2 * c2;
            int idx = (yy * 98 + x) * 32 + ((((e >> 3) ^ x) & 3) << 3) + (e & 7);
            *(unsigned*)&Xs[idx] = pk.u;
        }
        for (int i = tid; i < 9216; i += 256) {
            int c2 = i & 15; int co = (i >> 4) & 63; int tap = i >> 10;
            const float* p = wp + ((size_t)co * CC + ci0 + 2 * c2) * 9 + tap;
            union { f16 h[2]; unsigned u; } pk;
            pk.h[0] = (f16)p[0]; pk.h[1] = (f16)p[9];
            int e = 2 * c2;
            int idx = tap * WROW + co * 32 + ((((e >> 3) ^ co) & 3) << 3) + (e & 7);
            *(unsigned*)&Wl[idx] = pk.u;
        }
        __syncthreads();
        mfma_phase(Xs, Wl, w, aBase, d0, d1, d2, acc);
    }
}

struct GArgs {
    const float* in[3];
    const float* w[4][3];
    f16* G;
};

__global__ __launch_bounds__(256) void gates_mfma(GArgs A) {
    __shared__ __align__(16) f16 Xs[XSZ];
    __shared__ __align__(16) f16 Wl[WSZL];
    const int g = blockIdx.z, b = blockIdx.y, y0 = blockIdx.x * 4;
    const int tid = threadIdx.x;
    const int w = tid >> 6, lane = tid & 63;
    const int pxl = lane & 15, kg = lane >> 4;
    const int aBase = pxl * 32 + (((kg ^ pxl) & 3) << 3);
    const int d0 = (pxl + 0) * 32 + (((kg ^ (pxl + 0)) & 3) << 3);
    const int d1 = (pxl + 1) * 32 + (((kg ^ (pxl + 1)) & 3) << 3);
    const int d2 = (pxl + 2) * 32 + (((kg ^ (pxl + 2)) & 3) << 3);
    f32x4 acc[4][6];
#pragma unroll
    for (int mt = 0; mt < 4; ++mt)
#pragma unroll
        for (int nt = 0; nt < 6; ++nt) acc[mt][nt] = (f32x4){0.f, 0.f, 0.f, 0.f};
    for (int s = 0; s < 3; ++s) {
        const float* inp = A.in[s];
        const float* wp = A.w[g][s];
        if (!inp || !wp) continue;
        conv_section(inp + (size_t)b * CHW, wp, y0, tid, Xs, Wl, w, aBase, d0, d1, d2, acc);
    }
    f16* Gp = A.G + (size_t)(g * BB + b) * CHW;
    const int y = y0 + w;
#pragma unroll
    for (int mt = 0; mt < 4; ++mt)
#pragma unroll
        for (int r = 0; r < 4; ++r) {
            const int co = mt * 16 + kg * 4 + r;
            f16* rp = Gp + (size_t)co * HW + y * WW + pxl;
#pragma unroll
            for (int nt = 0; nt < 6; ++nt) rp[nt * 16] = (f16)acc[mt][nt][r];
        }
}

__global__ __launch_bounds__(256) void pointwise_c(const f16* __restrict__ G,
                                                   const float* __restrict__ cprev,
                                                   const float* __restrict__ bi,
                                                   const float* __restrict__ bf,
                                                   const float* __restrict__ bc,
                                                   float* __restrict__ cnew) {
    int flat = (blockIdx.x * 256 + threadIdx.x) * 4;
    if (flat >= BCHW) return;
    int co = (flat / HW) & 63;
    f16x4 gi = *(const f16x4*)(G + flat);
    f16x4 gf = *(const f16x4*)(G + (size_t)BCHW + flat);
    f16x4 gc = *(const f16x4*)(G + 2 * (size_t)BCHW + flat);
    float4 cp = make_float4(0.f, 0.f, 0.f, 0.f);
    if (cprev) cp = *(const float4*)(cprev + flat);
    float vbi = bi[co], vbf = bf[co], vbc = bc[co];
    float4 r;
    r.x = tanhf_((float)gc.x + vbc) * sigmoidf_((float)gi.x + vbi) + cp.x * sigmoidf_((float)gf.x + vbf);
    r.y = tanhf_((float)gc.y + vbc) * sigmoidf_((float)gi.y + vbi) + cp.y * sigmoidf_((float)gf.y + vbf);
    r.z = tanhf_((float)gc.z + vbc) * sigmoidf_((float)gi.z + vbi) + cp.z * sigmoidf_((float)gf.z + vbf);
    r.w = tanhf_((float)gc.w + vbc) * sigmoidf_((float)gi.w + vbi) + cp.w * sigmoidf_((float)gf.w + vbf);
    *(float4*)(cnew + flat) = r;
}

__global__ __launch_bounds__(256) void out_mfma(const float* __restrict__ cnew,
                                                const float* __restrict__ wp,
                                                const f16* __restrict__ Go,
                                                const float* __restrict__ bo,
                                                const float* __restrict__ bc,
                                                float* __restrict__ hout) {
    __shared__ __align__(16) f16 Xs[XSZ];
    __shared__ __align__(16) f16 Wl[WSZL];
    const int b = blockIdx.y, y0 = blockIdx.x * 4;
    const int tid = threadIdx.x;
    const int w = tid >> 6, lane = tid & 63;
    const int pxl = lane & 15, kg = lane >> 4;
    const int aBase = pxl * 32 + (((kg ^ pxl) & 3) << 3);
    const int d0 = (pxl + 0) * 32 + (((kg ^ (pxl + 0)) & 3) << 3);
    const int d1 = (pxl + 1) * 32 + (((kg ^ (pxl + 1)) & 3) << 3);
    const int d2 = (pxl + 2) * 32 + (((kg ^ (pxl + 2)) & 3) << 3);
    f32x4 acc[4][6];
#pragma unroll
    for (int mt = 0; mt < 4; ++mt)
#pragma unroll
        for (int nt = 0; nt < 6; ++nt) acc[mt][nt] = (f32x4){0.f, 0.f, 0.f, 0.f};
    const float* cb = cnew + (size_t)b * CHW;
    conv_section(cb, wp, y0, tid, Xs, Wl, w, aBase, d0, d1, d2, acc);
    const f16* Gb = Go + (size_t)b * CHW;
    float* hb = hout + (size_t)b * CHW;
    const int y = y0 + w;
#pragma unroll
    for (int mt = 0; mt < 4; ++mt)
#pragma unroll
        for (int r = 0; r < 4; ++r) {
            const int co = mt * 16 + kg * 4 + r;
            const float vbv = bo[co] + bc[co];
            const size_t off0 = (size_t)co * HW + y * WW + pxl;
#pragma unroll
            for (int nt = 0; nt < 6; ++nt) {
                size_t off = off0 + nt * 16;
                float opre = acc[mt][nt][r] + (float)Gb[off] + vbv;
                hb[off] = sigmoidf_(opre) * tanhf_(cb[off]);
            }
        }
}

// ============================================================================
// Host
// ============================================================================

extern "C" void kernel_launch(void* const* d_in, const int* in_sizes, int n_in,
                              void* d_out, int out_size, void* d_ws, size_t ws_size,
                              hipStream_t stream) {
    const float* x = (const float*)d_in[0];
    const float* w_[11];
    for (int i = 0; i < 11; ++i) w_[i] = (const float*)d_in[1 + i];
    const float* b_[4];
    for (int i = 0; i < 4; ++i) b_[i] = (const float*)d_in[12 + i];

    float* out = (float*)d_out;
    float* hs = out;               // [T,B,C,H,W]
    float* cs = out + TBCHW;       // [T,B,C,H,W]

    const size_t G_B = 4ull * GPLANE_F * 2ull;          // 37748736
    const size_t WF_B = 2ull * 10ull * WT_F * 2ull;     // 1474560
    const size_t NEED = 10ull * SLOT_B + G_B + WF_B;

    if (ws_size >= NEED) {
        char* ws = (char*)d_ws;
        f16* slots = (f16*)ws;                               // 10 padded slots
        f16* G = (f16*)(ws + 10ull * SLOT_B);
        f16* Wf = (f16*)(ws + 10ull * SLOT_B + G_B);

        WPtrs wps;
        for (int i = 0; i < 10; ++i) wps.p[i] = w_[i];      // by value: capture-safe

        wprep<<<dim3(9, 10, 2), 256, 0, stream>>>(wps, Wf);
        bzero<<<dim3(971), 256, 0, stream>>>((char*)slots);
        xprep<<<dim3(96 * BB, TT), 256, 0, stream>>>(x, slots);

        for (int l = 0; l < LL; ++l) {
            const f16* WT[10];
            for (int ti = 0; ti < 10; ++ti) WT[ti] = Wf + (size_t)(l * 10 + ti) * WT_F;
            const float* bi = b_[0] + l * CC;
            const float* bf = b_[1] + l * CC;
            const float* bc = b_[2] + l * CC;
            const float* bo = b_[3] + l * CC;

            for (int t = 0; t < TT; ++t) {
                f16* xt = slots + (size_t)t * SLOT_F;
                f16* hprev = (t == 0) ? nullptr : slots + (size_t)(t - 1) * SLOT_F;
                f16* cprev = (t == 0) ? nullptr
                                      : slots + (size_t)(8 + ((t - 1) & 1)) * SLOT_F;
                f16* cnew = slots + (size_t)(8 + (t & 1)) * SLOT_F;

                GArgsN a;
                if (t == 0) {
                    a.in[0] = xt; a.in[1] = xt; a.in[2] = xt;
                    a.w[0][0] = WT[0]; a.w[0][1] = WT[0]; a.w[0][2] = WT[0];
                    a.w[1][0] = WT[3]; a.w[1][1] = WT[3]; a.w[1][2] = WT[3];
                    a.w[2][0] = WT[6]; a.w[2][1] = WT[6]; a.w[2][2] = WT[6];
                    a.w[3][0] = WT[8]; a.w[3][1] = WT[8]; a.w[3][2] = WT[8];
                    a.nsecA = 1; a.nsecB = 1;
                } else {
                    a.in[0] = xt; a.in[1] = hprev; a.in[2] = cprev;
                    a.w[0][0] = WT[0]; a.w[0][1] = WT[1]; a.w[0][2] = WT[2];
                    a.w[1][0] = WT[3]; a.w[1][1] = WT[4]; a.w[1][2] = WT[5];
                    a.w[2][0] = WT[6]; a.w[2][1] = WT[7]; a.w[2][2] = WT[7];
                    a.w[3][0] = WT[8]; a.w[3][1] = WT[9]; a.w[3][2] = WT[9];
                    a.nsecA = 3; a.nsecB = 2;
                }
                a.G = G;
                gates_pair<<<dim3(384), 256, 0, stream>>>(a);
                pointwise_n<<<dim3(2304), 256, 0, stream>>>(
                    G, cprev, bi, bf, bc, cnew,
                    (l == 1) ? (cs + (size_t)t * BCHW) : nullptr);
                out_n<<<dim3(192), 256, 0, stream>>>(
                    cnew, WT[7], G + 3 * GPLANE_F, bo, bc,
                    xt,                                   // h f16 overwrites consumed x slot
                    (l == 1) ? (hs + (size_t)t * BCHW) : nullptr);
            }
        }
        return;
    }

    // ---------------- fallback: round-3 path (needs 75.5 MB) ----------------
    f16* G = (f16*)d_ws;
    float* c0 = (float*)d_ws + 2 * (size_t)BCHW;
    float* c1 = c0 + BCHW;

    for (int l = 0; l < LL; ++l) {
        const float* wxi = w_[0] + l * WSZ;
        const float* whi = w_[1] + l * WSZ;
        const float* wci = w_[2] + l * WSZ;
        const float* wxf = w_[3] + l * WSZ;
        const float* whf = w_[4] + l * WSZ;
        const float* wcf = w_[5] + l * WSZ;
        const float* wxc = w_[6] + l * WSZ;
        const float* whc = w_[7] + l * WSZ;
        const float* wxo = w_[8] + l * WSZ;
        const float* who = w_[9] + l * WSZ;
        const float* bi = b_[0] + l * CC;
        const float* bf = b_[1] + l * CC;
        const float* bc = b_[2] + l * CC;
        const float* bo = b_[3] + l * CC;

        for (int t = 0; t < TT; ++t) {
            const float* xt = (l == 0) ? (x + (size_t)t * BCHW) : (hs + (size_t)t * BCHW);
            const float* hprev = (t == 0) ? nullptr : (hs + (size_t)(t - 1) * BCHW);
            const float* cprev = (t == 0) ? nullptr
                : (l == 0 ? (((t - 1) & 1) ? c1 : c0) : (cs + (size_t)(t - 1) * BCHW));
            float* cnew = (l == 0) ? ((t & 1) ? c1 : c0) : (cs + (size_t)t * BCHW);

            GArgs a;
            a.in[0] = xt; a.in[1] = hprev; a.in[2] = cprev;
            a.w[0][0] = wxi; a.w[0][1] = whi; a.w[0][2] = wci;
            a.w[1][0] = wxf; a.w[1][1] = whf; a.w[1][2] = wcf;
            a.w[2][0] = wxc; a.w[2][1] = whc; a.w[2][2] = nullptr;
            a.w[3][0] = wxo; a.w[3][1] = who; a.w[3][2] = nullptr;
            a.G = G;
            gates_mfma<<<dim3(24, BB, 4), 256, 0, stream>>>(a);
            pointwise_c<<<dim3(BCHW / 1024), 256, 0, stream>>>(G, cprev, bi, bf, bc, cnew);
            out_mfma<<<dim3(24, BB), 256, 0, stream>>>(cnew, whc, G + (size_t)3 * BCHW,
                                                       bo, bc, hs + (size_t)t * BCHW);
        }
    }
}

// Round 13
// 1715.476 us; speedup vs baseline: 1.2264x; 1.2264x over previous
//
#include <hip/hip_runtime.h>
#include <math.h>

// Problem constants
#define TT 8
#define BB 8
#define CC 64
#define HH 96
#define WW 96
#define LL 2
#define HW   (HH * WW)            // 9216
#define CHW  (CC * HW)            // 589824
#define BCHW (BB * CHW)           // 4718592
#define TBCHW (TT * BCHW)         // 37748736
#define WSZ  (CC * CC * 9)        // 36864 (per-layer weight tensor, fp32 elems)

typedef _Float16 f16;
typedef __attribute__((ext_vector_type(8))) _Float16 f16x8;
typedef __attribute__((ext_vector_type(4))) _Float16 f16x4;
typedef __attribute__((ext_vector_type(4))) float f32x4;

__device__ __forceinline__ float sigmoidf_(float x) {
    return 1.0f / (1.0f + __expf(-x));
}
// fast tanh: 1 - 2/(e^{2x}+1); saturates correctly at +-inf
__device__ __forceinline__ float tanhf_(float x) {
    float e = __expf(2.f * x);
    return 1.f - 2.f / (e + 1.f);
}

// ============================================================================
// R9 (best known: 1715 us): dbuf DMA pipeline, 768-block gates, parallel pw.
//  - X and W staged via global_load_lds DMA into DOUBLE-BUFFERED LDS.
//  - Per phase: issue stage(p+1) -> other buffer, THEN mfma(p), THEN one
//    __syncthreads() (its vmcnt(0) drain lands after MFMA, so the DMA
//    transfer overlaps compute instead of serializing before it).
//  - LDS = 2*(37632+36864) = 148992 B -> 1 block/CU.
//  - Grid flattened with b in low 3 bits: XCD k caches batch k's slots.
// Padded activation slot: [B][98y][98x][64ci] f16, 128B/pixel, borders zero,
//   within each 64B half, chunk position p holds source chunk (p ^ x_pad)&3.
// Weight image per (layer,tensor): [half][tap][co][4 chunks][8 f16] = 73728 B,
//   chunk position p holds source chunk (p ^ co)&3.
// ============================================================================

#define SLOT_B   9834496ull          // 8b * 98*98 * 128 bytes per padded slot
#define PLANE_B  1229312ull          // 98*98*128 (per-b plane bytes)
#define SLOT_F   (SLOT_B / 2)        // f16 elems per slot
#define GPLANE_F 4718592ull          // 8b*9216*64 f16 per gate plane
#define WT_F     36864               // f16 elems per (layer,tensor) weight image
#define XHALF_F  18816               // f16 per X buffer (6*98*32)
#define WHALF_F  18432               // f16 per W buffer (9*64*32)

struct WPtrs { const float* p[10]; };

__device__ __forceinline__ void gl_lds16(const void* g, void* lds_base) {
    __builtin_amdgcn_global_load_lds(
        (const __attribute__((address_space(1))) unsigned int*)g,
        (__attribute__((address_space(3))) unsigned int*)lds_base, 16, 0, 0);
}

// ---------- prep: weights fp32 -> f16 image ----------
__global__ __launch_bounds__(256) void wprep(WPtrs wsrcs, f16* Wf) {
    const int tap = blockIdx.x, ti = blockIdx.y, l = blockIdx.z;
    const float* src = wsrcs.p[ti] + l * WSZ;
    f16* dst = Wf + (size_t)(l * 10 + ti) * WT_F;
    for (int r = 0; r < 16; ++r) {
        int lin = r * 256 + threadIdx.x;      // 0..4095
        int co = lin >> 6, ci = lin & 63;
        float v = src[(co * 64 + ci) * 9 + tap];
        int half = ci >> 5, e = ci & 31, s = e >> 3;
        int p = (s ^ co) & 3;
        dst[((half * 9 + tap) * 64 + co) * 32 + p * 8 + (e & 7)] = (f16)v;
    }
}

// ---------- prep: zero borders of the 10 padded slots ----------
__global__ __launch_bounds__(256) void bzero(char* slots) {
    unsigned u = blockIdx.x * 256 + threadIdx.x;
    if (u >= 248320u) return;                  // 10 bufs * 8b * 388 px * 8 chunks
    unsigned plane = u / 3104u;                // [buf][b] composite (80 planes)
    unsigned r = u % 3104u;
    unsigned i = r >> 3, c = r & 7;
    int y, x;
    if (i < 98)       { y = 0;           x = i; }
    else if (i < 196) { y = 97;          x = i - 98; }
    else if (i < 292) { y = i - 196 + 1; x = 0; }
    else              { y = i - 292 + 1; x = 97; }
    uint4 z = make_uint4(0, 0, 0, 0);
    *(uint4*)(slots + (size_t)plane * PLANE_B + (size_t)(y * 98 + x) * 128 + c * 16) = z;
}

// ---------- prep: x fp32 -> padded f16 slots ----------
__global__ __launch_bounds__(256) void xprep(const float* __restrict__ x, f16* slots) {
    const int t = blockIdx.y;
    const int b = blockIdx.x / 96, y = blockIdx.x % 96;
    f16* slot = slots + (size_t)t * SLOT_F;
    for (int r = 0; r < 3; ++r) {
        int u = r * 256 + threadIdx.x;         // 0..767
        int px = u >> 3, c = u & 7;
        int half = c >> 2, p = c & 3;
        int sc = (p ^ (px + 1)) & 3;           // source chunk for position p
        int ci0 = half * 32 + sc * 8;
        const float* sp = x + ((((size_t)t * BB + b) * CC + ci0) * HH + y) * WW + px;
        union { f16 h[8]; uint4 q; } pk;
#pragma unroll
        for (int j = 0; j < 8; ++j) pk.h[j] = (f16)sp[(size_t)j * HW];
        f16* dp = slot + ((size_t)b * 9604 + (y + 1) * 98 + (px + 1)) * 64 + half * 32 + p * 8;
        *(uint4*)dp = pk.q;
    }
}

// ---------- staging: DMA one phase (32 ci) of X-tile + W into given buffers ----------
__device__ __forceinline__ void stage_phase(const char* __restrict__ xb_h, int y0,
                                            const char* __restrict__ wsec_h,
                                            int w, int lane, f16* Xs, f16* Wl) {
    const char* xc = xb_h + (size_t)y0 * 12544;     // y0*98*128
    const int cb = w * 588;
#pragma unroll
    for (int i = 0; i < 9; ++i) {
        const int c = cb + i * 64 + lane;
        gl_lds16(xc + (size_t)(c >> 2) * 128 + (c & 3) * 16,
                 (char*)Xs + (size_t)(cb + i * 64) * 16);
    }
    if (lane < 12) {
        const int c = cb + 576 + lane;
        gl_lds16(xc + (size_t)(c >> 2) * 128 + (c & 3) * 16,
                 (char*)Xs + (size_t)(cb + 576) * 16);
    }
    const int cw = w * 576;
#pragma unroll
    for (int i = 0; i < 9; ++i) {
        gl_lds16(wsec_h + (size_t)(cw + i * 64 + lane) * 16,
                 (char*)Wl + (size_t)(cw + i * 64) * 16);
    }
}

// ---------- MFMA sweep over 9 taps for one phase ----------
__device__ __forceinline__ void mfma_phase(const f16* Xs, const f16* Wl,
                                           int w, int aBase, int d0, int d1, int d2,
                                           f32x4 acc[4][6]) {
#pragma unroll
    for (int tap = 0; tap < 9; ++tap) {
        const int dy = tap / 3, dx = tap % 3;
        const f16* Ar = &Wl[tap * 2048 + aBase];
        f16x8 a0 = *(const f16x8*)(Ar);
        f16x8 a1 = *(const f16x8*)(Ar + 512);
        f16x8 a2 = *(const f16x8*)(Ar + 1024);
        f16x8 a3 = *(const f16x8*)(Ar + 1536);
        const int doff = (dx == 0) ? d0 : (dx == 1) ? d1 : d2;
        const f16* Br = &Xs[(w + dy) * 3136 + doff];
#pragma unroll
        for (int nt = 0; nt < 6; ++nt) {
            f16x8 bf = *(const f16x8*)(Br + nt * 512);
            acc[0][nt] = __builtin_amdgcn_mfma_f32_16x16x32_f16(a0, bf, acc[0][nt], 0, 0, 0);
            acc[1][nt] = __builtin_amdgcn_mfma_f32_16x16x32_f16(a1, bf, acc[1][nt], 0, 0, 0);
            acc[2][nt] = __builtin_amdgcn_mfma_f32_16x16x32_f16(a2, bf, acc[2][nt], 0, 0, 0);
            acc[3][nt] = __builtin_amdgcn_mfma_f32_16x16x32_f16(a3, bf, acc[3][nt], 0, 0, 0);
        }
    }
}

struct GArgsN {
    const f16* in[3];       // COMPACTED padded slot bases (dups for unused)
    const f16* w[4][3];     // COMPACTED weight image bases per gate
    f16* G;                 // [4][b][9216][64] channel-last
    int nsecA, nsecB;       // valid sections: gates 0,1 / gates 2,3
};

// Grid 768 flat: b = bid&7 (XCD locality), g = (bid>>3)&3, ytile = bid>>5.
// Block 256 (4 waves), 1 block/CU (149 KB LDS). T3 2-stage pipeline.
__global__ __launch_bounds__(256, 1) void gates_n(GArgsN A) {
    __shared__ __align__(16) f16 Xs[2 * XHALF_F];
    __shared__ __align__(16) f16 Wl[2 * WHALF_F];
    const int bid = blockIdx.x;
    const int b = bid & 7, rr = bid >> 3, g = rr & 3, y0 = (rr >> 2) * 4;
    const int tid = threadIdx.x, w = tid >> 6, lane = tid & 63;
    const int pxl = lane & 15, kg = lane >> 4;

    const int aBase = pxl * 32 + (((kg ^ pxl) & 3) << 3);
    const int d0 = (pxl + 0) * 32 + (((kg ^ (pxl + 0)) & 3) << 3);
    const int d1 = (pxl + 1) * 32 + (((kg ^ (pxl + 1)) & 3) << 3);
    const int d2 = (pxl + 2) * 32 + (((kg ^ (pxl + 2)) & 3) << 3);

    f32x4 acc[4][6];
#pragma unroll
    for (int mt = 0; mt < 4; ++mt)
#pragma unroll
        for (int nt = 0; nt < 6; ++nt) acc[mt][nt] = (f32x4){0.f, 0.f, 0.f, 0.f};

    const char* xb0 = (const char*)(A.in[0] + (size_t)b * 614656);   // 9604*64
    const char* xb1 = (const char*)(A.in[1] + (size_t)b * 614656);
    const char* xb2 = (const char*)(A.in[2] + (size_t)b * 614656);
    const char* wp0 = (const char*)A.w[g][0];
    const char* wp1 = (const char*)A.w[g][1];
    const char* wp2 = (const char*)A.w[g][2];
    const int NP = 2 * ((g < 2) ? A.nsecA : A.nsecB);

    stage_phase(xb0, y0, wp0, w, lane, Xs, Wl);      // phase 0 -> buf 0
    __syncthreads();
    for (int p = 0; p < NP; ++p) {
        const int cur = p & 1;
        if (p + 1 < NP) {                            // issue next phase's DMA first
            const int s1 = (p + 1) >> 1, h1 = (p + 1) & 1;
            const char* xb_s = (s1 == 0) ? xb0 : (s1 == 1) ? xb1 : xb2;
            const char* wp_s = (s1 == 0) ? wp0 : (s1 == 1) ? wp1 : wp2;
            stage_phase(xb_s + h1 * 64, y0, wp_s + h1 * 36864, w, lane,
                        Xs + (cur ^ 1) * XHALF_F, Wl + (cur ^ 1) * WHALF_F);
        }
        mfma_phase(Xs + cur * XHALF_F, Wl + cur * WHALF_F,
                   w, aBase, d0, d1, d2, acc);       // overlaps the DMA transfer
        __syncthreads();                             // drain lands after MFMA
    }

    // epilogue: channel-last G write. pixel = (y0+w)*96 + nt*16+pxl, co = mt*16+kg*4+r
    f16* Gg = A.G + (size_t)g * GPLANE_F + ((size_t)b * 9216 + (y0 + w) * 96) * 64;
#pragma unroll
    for (int mt = 0; mt < 4; ++mt)
#pragma unroll
        for (int nt = 0; nt < 6; ++nt) {
            union { f16 h[4]; uint2 q; } pk;
#pragma unroll
            for (int r = 0; r < 4; ++r) pk.h[r] = (f16)acc[mt][nt][r];
            *(uint2*)(Gg + (size_t)(nt * 16 + pxl) * 64 + mt * 16 + kg * 4) = pk.q;
        }
}

// ---------- pointwise: gates -> c_new (f16 padded slot, + optional cs fp32) ----------
__global__ __launch_bounds__(256) void pointwise_n(const f16* __restrict__ G,
                                                   const f16* __restrict__ cprev,  // padded slot or null
                                                   const float* __restrict__ bi,
                                                   const float* __restrict__ bf,
                                                   const float* __restrict__ bc,
                                                   f16* __restrict__ cnew,          // padded slot
                                                   float* __restrict__ cs_out) {    // channel-first or null
    const int b = blockIdx.y;
    const int u = blockIdx.x * 256 + threadIdx.x;   // 0..73727
    const int pix = u >> 3, o = u & 7;
    const int ci0 = o * 8;
    const f16x8 gi = *(const f16x8*)(G + ((size_t)b * 9216 + pix) * 64 + ci0);
    const f16x8 gf = *(const f16x8*)(G + GPLANE_F + ((size_t)b * 9216 + pix) * 64 + ci0);
    const f16x8 gc = *(const f16x8*)(G + 2 * GPLANE_F + ((size_t)b * 9216 + pix) * 64 + ci0);
    const int py = pix / 96 + 1, pxp = pix % 96 + 1;
    const size_t pad_off = ((size_t)b * 9604 + py * 98 + pxp) * 64;
    const int half = o >> 2, p = ((o & 3) ^ pxp) & 3;
    const size_t sw_off = pad_off + half * 32 + p * 8;
    f16x8 cp = (f16x8)(_Float16)0.f;
    if (cprev) cp = *(const f16x8*)(cprev + sw_off);
    union { f16 h[8]; uint4 q; } outp;
    float cv[8];
#pragma unroll
    for (int j = 0; j < 8; ++j) {
        float vbi = bi[ci0 + j], vbf = bf[ci0 + j], vbc = bc[ci0 + j];
        float c = tanhf_((float)gc[j] + vbc) * sigmoidf_((float)gi[j] + vbi)
                + (float)cp[j] * sigmoidf_((float)gf[j] + vbf);
        cv[j] = c;
        outp.h[j] = (f16)c;
    }
    *(uint4*)(cnew + sw_off) = outp.q;
    if (cs_out) {
        float* op = cs_out + (size_t)b * CHW + (size_t)ci0 * HW + pix;
#pragma unroll
        for (int j = 0; j < 8; ++j) op[(size_t)j * HW] = cv[j];
    }
}

// ---------- out: h = sigmoid(conv(c_new,Whc)+Go+bo+bc) * tanh(c_new) ----------
// Grid 192 flat: b = bid&7, ytile = bid>>3. Same pipeline, NP=2.
__global__ __launch_bounds__(256, 1) void out_n(const f16* __restrict__ cnew,   // padded slot
                                                const f16* __restrict__ whc,    // weight image
                                                const f16* __restrict__ Go,     // G plane 3
                                                const float* __restrict__ bo,
                                                const float* __restrict__ bc,
                                                f16* __restrict__ hslot,        // padded slot
                                                float* __restrict__ hs_out) {   // or null
    __shared__ __align__(16) f16 Xs[2 * XHALF_F];
    __shared__ __align__(16) f16 Wl[2 * WHALF_F];
    const int bid = blockIdx.x;
    const int b = bid & 7, y0 = (bid >> 3) * 4;
    const int tid = threadIdx.x, w = tid >> 6, lane = tid & 63;
    const int pxl = lane & 15, kg = lane >> 4;

    const int aBase = pxl * 32 + (((kg ^ pxl) & 3) << 3);
    const int d0 = (pxl + 0) * 32 + (((kg ^ (pxl + 0)) & 3) << 3);
    const int d1 = (pxl + 1) * 32 + (((kg ^ (pxl + 1)) & 3) << 3);
    const int d2 = (pxl + 2) * 32 + (((kg ^ (pxl + 2)) & 3) << 3);

    f32x4 acc[4][6];
#pragma unroll
    for (int mt = 0; mt < 4; ++mt)
#pragma unroll
        for (int nt = 0; nt < 6; ++nt) acc[mt][nt] = (f32x4){0.f, 0.f, 0.f, 0.f};

    const char* xb = (const char*)(cnew + (size_t)b * 614656);
    stage_phase(xb, y0, (const char*)whc, w, lane, Xs, Wl);
    __syncthreads();
    for (int p = 0; p < 2; ++p) {
        const int cur = p & 1;
        if (p == 0)
            stage_phase(xb + 64, y0, (const char*)whc + 36864, w, lane,
                        Xs + XHALF_F, Wl + WHALF_F);
        mfma_phase(Xs + cur * XHALF_F, Wl + cur * WHALF_F,
                   w, aBase, d0, d1, d2, acc);
        __syncthreads();
    }

    const int y = y0 + w;
#pragma unroll
    for (int mt = 0; mt < 4; ++mt) {
        const int cob = mt * 16 + kg * 4;
        float vb[4];
#pragma unroll
        for (int r = 0; r < 4; ++r) vb[r] = bo[cob + r] + bc[cob + r];
        const int half = mt >> 1;                          // (cob>>5)
        const int sq = (mt * 2 + (kg >> 1)) & 3;           // ((cob&31)>>3)
        const int lo4 = (kg & 1) * 4;                      // (cob&7)
#pragma unroll
        for (int nt = 0; nt < 6; ++nt) {
            const int px = nt * 16 + pxl;
            const int pix = y * 96 + px;
            const size_t pad_off = ((size_t)b * 9604 + (y + 1) * 98 + (px + 1)) * 64;
            const int p = (sq ^ (px + 1)) & 3;
            const size_t qoff = pad_off + half * 32 + p * 8 + lo4;
            f16x4 cq = *(const f16x4*)(cnew + qoff);
            f16x4 gq = *(const f16x4*)(Go + ((size_t)b * 9216 + pix) * 64 + cob);
            union { f16 h[4]; uint2 q; } hq;
            float hv[4];
#pragma unroll
            for (int r = 0; r < 4; ++r) {
                float opre = acc[mt][nt][r] + (float)gq[r] + vb[r];
                hv[r] = sigmoidf_(opre) * tanhf_((float)cq[r]);
                hq.h[r] = (f16)hv[r];
            }
            *(uint2*)(hslot + qoff) = hq.q;
            if (hs_out) {
                float* op = hs_out + (size_t)b * CHW + (size_t)cob * HW + pix;
#pragma unroll
                for (int r = 0; r < 4; ++r) op[(size_t)r * HW] = hv[r];
            }
        }
    }
}

// ============================================================================
// FALLBACK PATH (round-3 kernels, ws budget 75.5 MB)
// ============================================================================

#define XROW 3136
#define XSZ  (6 * XROW)
#define WROW 2048
#define WSZL (9 * WROW)

__device__ __forceinline__ void conv_section(
    const float* __restrict__ inb, const float* __restrict__ wp,
    int y0, int tid, f16* Xs, f16* Wl,
    int w, int aBase, int d0, int d1, int d2, f32x4 acc[4][6])
{
    for (int ci0 = 0; ci0 < 64; ci0 += 32) {
        __syncthreads();
        for (int i = tid; i < 9408; i += 256) {
            int x = i % 98; int r = i / 98; int yy = r % 6; int c2 = r / 6;
            int gy = y0 - 1 + yy, gx = x - 1;
            float v0 = 0.f, v1 = 0.f;
            if ((unsigned)gy < 96u && (unsigned)gx < 96u) {
                const float* p = inb + (size_t)(ci0 + 2 * c2) * HW + gy * WW + gx;
                v0 = p[0]; v1 = p[HW];
            }
            union { f16 h[2]; unsigned u; } pk;
            pk.h[0] = (f16)v0; pk.h[1] = (f16)v1;
            int e = 2 * c2;
            int idx = (yy * 98 + x) * 32 + ((((e >> 3) ^ x) & 3) << 3) + (e & 7);
            *(unsigned*)&Xs[idx] = pk.u;
        }
        for (int i = tid; i < 9216; i += 256) {
            int c2 = i & 15; int co = (i >> 4) & 63; int tap = i >> 10;
            const float* p = wp + ((size_t)co * CC + ci0 + 2 * c2) * 9 + tap;
            union { f16 h[2]; unsigned u; } pk;
            pk.h[0] = (f16)p[0]; pk.h[1] = (f16)p[9];
            int e = 2 * c2;
            int idx = tap * WROW + co * 32 + ((((e >> 3) ^ co) & 3) << 3) + (e & 7);
            *(unsigned*)&Wl[idx] = pk.u;
        }
        __syncthreads();
        mfma_phase(Xs, Wl, w, aBase, d0, d1, d2, acc);
    }
}

struct GArgs {
    const float* in[3];
    const float* w[4][3];
    f16* G;
};

__global__ __launch_bounds__(256) void gates_mfma(GArgs A) {
    __shared__ __align__(16) f16 Xs[XSZ];
    __shared__ __align__(16) f16 Wl[WSZL];
    const int g = blockIdx.z, b = blockIdx.y, y0 = blockIdx.x * 4;
    const int tid = threadIdx.x;
    const int w = tid >> 6, lane = tid & 63;
    const int pxl = lane & 15, kg = lane >> 4;
    const int aBase = pxl * 32 + (((kg ^ pxl) & 3) << 3);
    const int d0 = (pxl + 0) * 32 + (((kg ^ (pxl + 0)) & 3) << 3);
    const int d1 = (pxl + 1) * 32 + (((kg ^ (pxl + 1)) & 3) << 3);
    const int d2 = (pxl + 2) * 32 + (((kg ^ (pxl + 2)) & 3) << 3);
    f32x4 acc[4][6];
#pragma unroll
    for (int mt = 0; mt < 4; ++mt)
#pragma unroll
        for (int nt = 0; nt < 6; ++nt) acc[mt][nt] = (f32x4){0.f, 0.f, 0.f, 0.f};
    for (int s = 0; s < 3; ++s) {
        const float* inp = A.in[s];
        const float* wp = A.w[g][s];
        if (!inp || !wp) continue;
        conv_section(inp + (size_t)b * CHW, wp, y0, tid, Xs, Wl, w, aBase, d0, d1, d2, acc);
    }
    f16* Gp = A.G + (size_t)(g * BB + b) * CHW;
    const int y = y0 + w;
#pragma unroll
    for (int mt = 0; mt < 4; ++mt)
#pragma unroll
        for (int r = 0; r < 4; ++r) {
            const int co = mt * 16 + kg * 4 + r;
            f16* rp = Gp + (size_t)co * HW + y * WW + pxl;
#pragma unroll
            for (int nt = 0; nt < 6; ++nt) rp[nt * 16] = (f16)acc[mt][nt][r];
        }
}

__global__ __launch_bounds__(256) void pointwise_c(const f16* __restrict__ G,
                                                   const float* __restrict__ cprev,
                                                   const float* __restrict__ bi,
                                                   const float* __restrict__ bf,
                                                   const float* __restrict__ bc,
                                                   float* __restrict__ cnew) {
    int flat = (blockIdx.x * 256 + threadIdx.x) * 4;
    if (flat >= BCHW) return;
    int co = (flat / HW) & 63;
    f16x4 gi = *(const f16x4*)(G + flat);
    f16x4 gf = *(const f16x4*)(G + (size_t)BCHW + flat);
    f16x4 gc = *(const f16x4*)(G + 2 * (size_t)BCHW + flat);
    float4 cp = make_float4(0.f, 0.f, 0.f, 0.f);
    if (cprev) cp = *(const float4*)(cprev + flat);
    float vbi = bi[co], vbf = bf[co], vbc = bc[co];
    float4 r;
    r.x = tanhf_((float)gc.x + vbc) * sigmoidf_((float)gi.x + vbi) + cp.x * sigmoidf_((float)gf.x + vbf);
    r.y = tanhf_((float)gc.y + vbc) * sigmoidf_((float)gi.y + vbi) + cp.y * sigmoidf_((float)gf.y + vbf);
    r.z = tanhf_((float)gc.z + vbc) * sigmoidf_((float)gi.z + vbi) + cp.z * sigmoidf_((float)gf.z + vbf);
    r.w = tanhf_((float)gc.w + vbc) * sigmoidf_((float)gi.w + vbi) + cp.w * sigmoidf_((float)gf.w + vbf);
    *(float4*)(cnew + flat) = r;
}

__global__ __launch_bounds__(256) void out_mfma(const float* __restrict__ cnew,
                                                const float* __restrict__ wp,
                                                const f16* __restrict__ Go,
                                                const float* __restrict__ bo,
                                                const float* __restrict__ bc,
                                                float* __restrict__ hout) {
    __shared__ __align__(16) f16 Xs[XSZ];
    __shared__ __align__(16) f16 Wl[WSZL];
    const int b = blockIdx.y, y0 = blockIdx.x * 4;
    const int tid = threadIdx.x;
    const int w = tid >> 6, lane = tid & 63;
    const int pxl = lane & 15, kg = lane >> 4;
    const int aBase = pxl * 32 + (((kg ^ pxl) & 3) << 3);
    const int d0 = (pxl + 0) * 32 + (((kg ^ (pxl + 0)) & 3) << 3);
    const int d1 = (pxl + 1) * 32 + (((kg ^ (pxl + 1)) & 3) << 3);
    const int d2 = (pxl + 2) * 32 + (((kg ^ (pxl + 2)) & 3) << 3);
    f32x4 acc[4][6];
#pragma unroll
    for (int mt = 0; mt < 4; ++mt)
#pragma unroll
        for (int nt = 0; nt < 6; ++nt) acc[mt][nt] = (f32x4){0.f, 0.f, 0.f, 0.f};
    const float* cb = cnew + (size_t)b * CHW;
    conv_section(cb, wp, y0, tid, Xs, Wl, w, aBase, d0, d1, d2, acc);
    const f16* Gb = Go + (size_t)b * CHW;
    float* hb = hout + (size_t)b * CHW;
    const int y = y0 + w;
#pragma unroll
    for (int mt = 0; mt < 4; ++mt)
#pragma unroll
        for (int r = 0; r < 4; ++r) {
            const int co = mt * 16 + kg * 4 + r;
            const float vbv = bo[co] + bc[co];
            const size_t off0 = (size_t)co * HW + y * WW + pxl;
#pragma unroll
            for (int nt = 0; nt < 6; ++nt) {
                size_t off = off0 + nt * 16;
                float opre = acc[mt][nt][r] + (float)Gb[off] + vbv;
                hb[off] = sigmoidf_(opre) * tanhf_(cb[off]);
            }
        }
}

// ============================================================================
// Host
// ============================================================================

extern "C" void kernel_launch(void* const* d_in, const int* in_sizes, int n_in,
                              void* d_out, int out_size, void* d_ws, size_t ws_size,
                              hipStream_t stream) {
    const float* x = (const float*)d_in[0];
    const float* w_[11];
    for (int i = 0; i < 11; ++i) w_[i] = (const float*)d_in[1 + i];
    const float* b_[4];
    for (int i = 0; i < 4; ++i) b_[i] = (const float*)d_in[12 + i];

    float* out = (float*)d_out;
    float* hs = out;               // [T,B,C,H,W]
    float* cs = out + TBCHW;       // [T,B,C,H,W]

    const size_t G_B = 4ull * GPLANE_F * 2ull;          // 37748736
    const size_t WF_B = 2ull * 10ull * WT_F * 2ull;     // 1474560
    const size_t NEED = 10ull * SLOT_B + G_B + WF_B;

    if (ws_size >= NEED) {
        char* ws = (char*)d_ws;
        f16* slots = (f16*)ws;                               // 10 padded slots
        f16* G = (f16*)(ws + 10ull * SLOT_B);
        f16* Wf = (f16*)(ws + 10ull * SLOT_B + G_B);

        WPtrs wps;
        for (int i = 0; i < 10; ++i) wps.p[i] = w_[i];      // by value: capture-safe

        wprep<<<dim3(9, 10, 2), 256, 0, stream>>>(wps, Wf);
        bzero<<<dim3(971), 256, 0, stream>>>((char*)slots);
        xprep<<<dim3(96 * BB, TT), 256, 0, stream>>>(x, slots);

        for (int l = 0; l < LL; ++l) {
            const f16* WT[10];
            for (int ti = 0; ti < 10; ++ti) WT[ti] = Wf + (size_t)(l * 10 + ti) * WT_F;
            const float* bi = b_[0] + l * CC;
            const float* bf = b_[1] + l * CC;
            const float* bc = b_[2] + l * CC;
            const float* bo = b_[3] + l * CC;

            for (int t = 0; t < TT; ++t) {
                f16* xt = slots + (size_t)t * SLOT_F;
                f16* hprev = (t == 0) ? nullptr : slots + (size_t)(t - 1) * SLOT_F;
                f16* cprev = (t == 0) ? nullptr
                                      : slots + (size_t)(8 + ((t - 1) & 1)) * SLOT_F;
                f16* cnew = slots + (size_t)(8 + (t & 1)) * SLOT_F;

                GArgsN a;
                if (t == 0) {
                    // only section 0 (x) valid; dup pointers for unused slots
                    a.in[0] = xt; a.in[1] = xt; a.in[2] = xt;
                    a.w[0][0] = WT[0]; a.w[0][1] = WT[0]; a.w[0][2] = WT[0];
                    a.w[1][0] = WT[3]; a.w[1][1] = WT[3]; a.w[1][2] = WT[3];
                    a.w[2][0] = WT[6]; a.w[2][1] = WT[6]; a.w[2][2] = WT[6];
                    a.w[3][0] = WT[8]; a.w[3][1] = WT[8]; a.w[3][2] = WT[8];
                    a.nsecA = 1; a.nsecB = 1;
                } else {
                    a.in[0] = xt; a.in[1] = hprev; a.in[2] = cprev;
                    a.w[0][0] = WT[0]; a.w[0][1] = WT[1]; a.w[0][2] = WT[2];
                    a.w[1][0] = WT[3]; a.w[1][1] = WT[4]; a.w[1][2] = WT[5];
                    a.w[2][0] = WT[6]; a.w[2][1] = WT[7]; a.w[2][2] = WT[7];
                    a.w[3][0] = WT[8]; a.w[3][1] = WT[9]; a.w[3][2] = WT[9];
                    a.nsecA = 3; a.nsecB = 2;
                }
                a.G = G;
                gates_n<<<dim3(768), 256, 0, stream>>>(a);
                pointwise_n<<<dim3(288, BB), 256, 0, stream>>>(
                    G, cprev, bi, bf, bc, cnew,
                    (l == 1) ? (cs + (size_t)t * BCHW) : nullptr);
                out_n<<<dim3(192), 256, 0, stream>>>(
                    cnew, WT[7], G + 3 * GPLANE_F, bo, bc,
                    xt,                                   // h f16 overwrites consumed x slot
                    (l == 1) ? (hs + (size_t)t * BCHW) : nullptr);
            }
        }
        return;
    }

    // ---------------- fallback: round-3 path (needs 75.5 MB) ----------------
    f16* G = (f16*)d_ws;
    float* c0 = (float*)d_ws + 2 * (size_t)BCHW;
    float* c1 = c0 + BCHW;

    for (int l = 0; l < LL; ++l) {
        const float* wxi = w_[0] + l * WSZ;
        const float* whi = w_[1] + l * WSZ;
        const float* wci = w_[2] + l * WSZ;
        const float* wxf = w_[3] + l * WSZ;
        const float* whf = w_[4] + l * WSZ;
        const float* wcf = w_[5] + l * WSZ;
        const float* wxc = w_[6] + l * WSZ;
        const float* whc = w_[7] + l * WSZ;
        const float* wxo = w_[8] + l * WSZ;
        const float* who = w_[9] + l * WSZ;
        const float* bi = b_[0] + l * CC;
        const float* bf = b_[1] + l * CC;
        const float* bc = b_[2] + l * CC;
        const float* bo = b_[3] + l * CC;

        for (int t = 0; t < TT; ++t) {
            const float* xt = (l == 0) ? (x + (size_t)t * BCHW) : (hs + (size_t)t * BCHW);
            const float* hprev = (t == 0) ? nullptr : (hs + (size_t)(t - 1) * BCHW);
            const float* cprev = (t == 0) ? nullptr
                : (l == 0 ? (((t - 1) & 1) ? c1 : c0) : (cs + (size_t)(t - 1) * BCHW));
            float* cnew = (l == 0) ? ((t & 1) ? c1 : c0) : (cs + (size_t)t * BCHW);

            GArgs a;
            a.in[0] = xt; a.in[1] = hprev; a.in[2] = cprev;
            a.w[0][0] = wxi; a.w[0][1] = whi; a.w[0][2] = wci;
            a.w[1][0] = wxf; a.w[1][1] = whf; a.w[1][2] = wcf;
            a.w[2][0] = wxc; a.w[2][1] = whc; a.w[2][2] = nullptr;
            a.w[3][0] = wxo; a.w[3][1] = who; a.w[3][2] = nullptr;
            a.G = G;
            gates_mfma<<<dim3(24, BB, 4), 256, 0, stream>>>(a);
            pointwise_c<<<dim3(BCHW / 1024), 256, 0, stream>>>(G, cprev, bi, bf, bc, cnew);
            out_mfma<<<dim3(24, BB), 256, 0, stream>>>(cnew, whc, G + (size_t)3 * BCHW,
                                                       bo, bc, hs + (size_t)t * BCHW);
        }
    }
}